// Round 1
// baseline (6320.584 us; speedup 1.0000x reference)
//
#include <hip/hip_runtime.h>

#define LRELU_SLOPE 0.2f

__device__ __forceinline__ float lrelu(float x) { return x > 0.f ? x : LRELU_SLOPE * x; }
__device__ __forceinline__ float eexp(float x)  { return __expf(fminf(x, 80.f)); }

// ---------------------------------------------------------------------------
// K1: per-node  h1 = x @ W1  [N,32]; attention logits a_src1/a_dst1 [N,4];
//     self-loop init: denom1[n,h] = exp(lrelu(as+ad)); acc1[n,:] = denom_init*h1
// ---------------------------------------------------------------------------
__global__ __launch_bounds__(256) void k1_node(
    const float* __restrict__ x, const float* __restrict__ W1,
    const float* __restrict__ att_src1, const float* __restrict__ att_dst1,
    float* __restrict__ h1, float* __restrict__ a_src1, float* __restrict__ a_dst1,
    float* __restrict__ denom1, float* __restrict__ acc1, int N)
{
    __shared__ float sW[512];   // 16x32
    __shared__ float sAs[32], sAd[32];
    int tid = threadIdx.x;
    for (int i = tid; i < 512; i += 256) sW[i] = W1[i];
    if (tid < 32) { sAs[tid] = att_src1[tid]; sAd[tid] = att_dst1[tid]; }
    __syncthreads();
    int n = blockIdx.x * 256 + tid;
    if (n >= N) return;

    float xr[16];
    const float4* xp = (const float4*)(x + (size_t)n * 16);
    float4 v0 = xp[0], v1 = xp[1], v2 = xp[2], v3 = xp[3];
    xr[0]=v0.x; xr[1]=v0.y; xr[2]=v0.z;  xr[3]=v0.w;
    xr[4]=v1.x; xr[5]=v1.y; xr[6]=v1.z;  xr[7]=v1.w;
    xr[8]=v2.x; xr[9]=v2.y; xr[10]=v2.z; xr[11]=v2.w;
    xr[12]=v3.x;xr[13]=v3.y;xr[14]=v3.z; xr[15]=v3.w;

    float h[32];
#pragma unroll
    for (int j = 0; j < 32; ++j) {
        float acc = 0.f;
#pragma unroll
        for (int i = 0; i < 16; ++i) acc = fmaf(xr[i], sW[i * 32 + j], acc);
        h[j] = acc;
    }

    float asr[4], adr[4], w[4];
#pragma unroll
    for (int hh = 0; hh < 4; ++hh) {
        float as = 0.f, ad = 0.f;
#pragma unroll
        for (int c = 0; c < 8; ++c) {
            as = fmaf(h[hh * 8 + c], sAs[hh * 8 + c], as);
            ad = fmaf(h[hh * 8 + c], sAd[hh * 8 + c], ad);
        }
        asr[hh] = as; adr[hh] = ad;
        w[hh] = eexp(lrelu(as + ad));     // self-loop weight
    }

    float4* h1p = (float4*)(h1 + (size_t)n * 32);
    float4* acp = (float4*)(acc1 + (size_t)n * 32);
#pragma unroll
    for (int j = 0; j < 32; j += 4) {
        float ww = w[j >> 3];   // j..j+3 share the same head (8 | grouping of 4)
        h1p[j >> 2] = make_float4(h[j], h[j+1], h[j+2], h[j+3]);
        acp[j >> 2] = make_float4(ww*h[j], ww*h[j+1], ww*h[j+2], ww*h[j+3]);
    }
    *(float4*)(a_src1 + (size_t)n * 4) = make_float4(asr[0], asr[1], asr[2], asr[3]);
    *(float4*)(a_dst1 + (size_t)n * 4) = make_float4(adr[0], adr[1], adr[2], adr[3]);
    *(float4*)(denom1 + (size_t)n * 4) = make_float4(w[0], w[1], w[2], w[3]);
}

// ---------------------------------------------------------------------------
// K2: per-edge layer-1 scatter: w_h = exp(lrelu(as[s,h]+ad[d,h]));
//     denom1[d,h] += w_h; acc1[d, h*8+c] += w_h * h1[s, h*8+c]
// ---------------------------------------------------------------------------
__global__ __launch_bounds__(256) void k2_edge(
    const int* __restrict__ src, const int* __restrict__ dst,
    const float* __restrict__ a_src1, const float* __restrict__ a_dst1,
    const float* __restrict__ h1,
    float* __restrict__ denom1, float* __restrict__ acc1, int E)
{
    int e = blockIdx.x * blockDim.x + threadIdx.x;
    if (e >= E) return;
    int s = src[e], d = dst[e];
    float4 as = *(const float4*)(a_src1 + (size_t)s * 4);
    float4 ad = *(const float4*)(a_dst1 + (size_t)d * 4);
    float w[4];
    w[0] = eexp(lrelu(as.x + ad.x));
    w[1] = eexp(lrelu(as.y + ad.y));
    w[2] = eexp(lrelu(as.z + ad.z));
    w[3] = eexp(lrelu(as.w + ad.w));

    float* dn = denom1 + (size_t)d * 4;
    unsafeAtomicAdd(dn + 0, w[0]);
    unsafeAtomicAdd(dn + 1, w[1]);
    unsafeAtomicAdd(dn + 2, w[2]);
    unsafeAtomicAdd(dn + 3, w[3]);

    const float* hs = h1 + (size_t)s * 32;
    float* ac = acc1 + (size_t)d * 32;
#pragma unroll
    for (int hh = 0; hh < 4; ++hh) {
        float ww = w[hh];
        float4 hv0 = *(const float4*)(hs + hh * 8);
        float4 hv1 = *(const float4*)(hs + hh * 8 + 4);
        unsafeAtomicAdd(ac + hh*8 + 0, ww * hv0.x);
        unsafeAtomicAdd(ac + hh*8 + 1, ww * hv0.y);
        unsafeAtomicAdd(ac + hh*8 + 2, ww * hv0.z);
        unsafeAtomicAdd(ac + hh*8 + 3, ww * hv0.w);
        unsafeAtomicAdd(ac + hh*8 + 4, ww * hv1.x);
        unsafeAtomicAdd(ac + hh*8 + 5, ww * hv1.y);
        unsafeAtomicAdd(ac + hh*8 + 6, ww * hv1.z);
        unsafeAtomicAdd(ac + hh*8 + 7, ww * hv1.w);
    }
}

// ---------------------------------------------------------------------------
// K3: per-node layer-1 epilogue + layer-2 prologue:
//     o = elu(acc1/denom1 + b1); h2 = o @ W2; as2/ad2 = h2*att2;
//     layer-2 self-loop init for denom2/acc2
// ---------------------------------------------------------------------------
__global__ __launch_bounds__(256) void k3_node(
    const float* __restrict__ acc1, const float* __restrict__ denom1,
    const float* __restrict__ b1, const float* __restrict__ W2,
    const float* __restrict__ att_src2, const float* __restrict__ att_dst2,
    float* __restrict__ h2, float* __restrict__ as2, float* __restrict__ ad2,
    float* __restrict__ denom2, float* __restrict__ acc2, int N)
{
    __shared__ float sb[32], sw[32];
    int tid = threadIdx.x;
    if (tid < 32) { sb[tid] = b1[tid]; sw[tid] = W2[tid]; }
    __syncthreads();
    int n = blockIdx.x * 256 + tid;
    if (n >= N) return;

    const float* ar = acc1 + (size_t)n * 32;
    float4 dq = *(const float4*)(denom1 + (size_t)n * 4);
    float dr4[4] = { dq.x + 1e-16f, dq.y + 1e-16f, dq.z + 1e-16f, dq.w + 1e-16f };

    float h2v = 0.f;
#pragma unroll
    for (int j = 0; j < 32; ++j) {
        float o = ar[j] / dr4[j >> 3] + sb[j];
        o = o > 0.f ? o : (__expf(o) - 1.f);   // ELU (alpha=1)
        h2v = fmaf(o, sw[j], h2v);
    }
    float s2 = att_src2[0], d2 = att_dst2[0];
    float a2s = h2v * s2, a2d = h2v * d2;
    h2[n] = h2v; as2[n] = a2s; ad2[n] = a2d;
    float w = eexp(lrelu(a2s + a2d));          // self-loop
    denom2[n] = w;
    acc2[n]   = w * h2v;
}

// ---------------------------------------------------------------------------
// K4: per-edge layer-2 scatter (1 head, 1 channel)
// ---------------------------------------------------------------------------
__global__ __launch_bounds__(256) void k4_edge(
    const int* __restrict__ src, const int* __restrict__ dst,
    const float* __restrict__ as2, const float* __restrict__ ad2,
    const float* __restrict__ h2,
    float* __restrict__ denom2, float* __restrict__ acc2, int E)
{
    int e = blockIdx.x * blockDim.x + threadIdx.x;
    if (e >= E) return;
    int s = src[e], d = dst[e];
    float w = eexp(lrelu(as2[s] + ad2[d]));
    unsafeAtomicAdd(denom2 + d, w);
    unsafeAtomicAdd(acc2 + d, w * h2[s]);
}

// ---------------------------------------------------------------------------
// K5: final output
// ---------------------------------------------------------------------------
__global__ __launch_bounds__(256) void k5_node(
    const float* __restrict__ acc2, const float* __restrict__ denom2,
    const float* __restrict__ b2, float* __restrict__ out, int N)
{
    int n = blockIdx.x * 256 + threadIdx.x;
    if (n >= N) return;
    out[n] = acc2[n] / (denom2[n] + 1e-16f) + b2[0];
}

extern "C" void kernel_launch(void* const* d_in, const int* in_sizes, int n_in,
                              void* d_out, int out_size, void* d_ws, size_t ws_size,
                              hipStream_t stream)
{
    const float* x        = (const float*)d_in[0];
    const int*   ei       = (const int*)d_in[1];
    const float* W1       = (const float*)d_in[2];
    const float* att_src1 = (const float*)d_in[3];
    const float* att_dst1 = (const float*)d_in[4];
    const float* b1       = (const float*)d_in[5];
    const float* W2       = (const float*)d_in[6];
    const float* att_src2 = (const float*)d_in[7];
    const float* att_dst2 = (const float*)d_in[8];
    const float* b2       = (const float*)d_in[9];

    const int N = in_sizes[0] / 16;
    const int E = in_sizes[1] / 2;
    const int* src = ei;
    const int* dst = ei + E;

    // workspace layout (floats)
    float* w = (float*)d_ws;
    float* h1     = w;                 // N*32
    float* a_src1 = h1     + (size_t)N * 32;   // N*4
    float* a_dst1 = a_src1 + (size_t)N * 4;    // N*4
    float* denom1 = a_dst1 + (size_t)N * 4;    // N*4
    float* acc1   = denom1 + (size_t)N * 4;    // N*32
    float* h2     = acc1   + (size_t)N * 32;   // N
    float* as2    = h2     + (size_t)N;        // N
    float* ad2    = as2    + (size_t)N;        // N
    float* denom2 = ad2    + (size_t)N;        // N
    float* acc2   = denom2 + (size_t)N;        // N

    const int nb_n = (N + 255) / 256;
    const int nb_e = (E + 255) / 256;

    k1_node<<<nb_n, 256, 0, stream>>>(x, W1, att_src1, att_dst1,
                                      h1, a_src1, a_dst1, denom1, acc1, N);
    k2_edge<<<nb_e, 256, 0, stream>>>(src, dst, a_src1, a_dst1, h1,
                                      denom1, acc1, E);
    k3_node<<<nb_n, 256, 0, stream>>>(acc1, denom1, b1, W2, att_src2, att_dst2,
                                      h2, as2, ad2, denom2, acc2, N);
    k4_edge<<<nb_e, 256, 0, stream>>>(src, dst, as2, ad2, h2, denom2, acc2, E);
    k5_node<<<nb_n, 256, 0, stream>>>(acc2, denom2, b2, (float*)d_out, N);
}

// Round 2
// 619.241 us; speedup vs baseline: 10.2070x; 10.2070x over previous
//
#include <hip/hip_runtime.h>

#define LRELU_SLOPE 0.2f

__device__ __forceinline__ float lrelu(float x) { return x > 0.f ? x : LRELU_SLOPE * x; }
__device__ __forceinline__ float eexp(float x)  { return __expf(fminf(x, 80.f)); }

// ---------------------------------------------------------------------------
// K1: per-node  h1 = x @ W1  [N,32]; attention logits a_src1/a_dst1 [N,4]
// ---------------------------------------------------------------------------
__global__ __launch_bounds__(256) void k1_node(
    const float* __restrict__ x, const float* __restrict__ W1,
    const float* __restrict__ att_src1, const float* __restrict__ att_dst1,
    float* __restrict__ h1, float* __restrict__ a_src1, float* __restrict__ a_dst1,
    int N)
{
    __shared__ float sW[512];   // 16x32
    __shared__ float sAs[32], sAd[32];
    int tid = threadIdx.x;
    for (int i = tid; i < 512; i += 256) sW[i] = W1[i];
    if (tid < 32) { sAs[tid] = att_src1[tid]; sAd[tid] = att_dst1[tid]; }
    __syncthreads();
    int n = blockIdx.x * 256 + tid;
    if (n >= N) return;

    float xr[16];
    const float4* xp = (const float4*)(x + (size_t)n * 16);
    float4 v0 = xp[0], v1 = xp[1], v2 = xp[2], v3 = xp[3];
    xr[0]=v0.x; xr[1]=v0.y; xr[2]=v0.z;  xr[3]=v0.w;
    xr[4]=v1.x; xr[5]=v1.y; xr[6]=v1.z;  xr[7]=v1.w;
    xr[8]=v2.x; xr[9]=v2.y; xr[10]=v2.z; xr[11]=v2.w;
    xr[12]=v3.x;xr[13]=v3.y;xr[14]=v3.z; xr[15]=v3.w;

    float h[32];
#pragma unroll
    for (int j = 0; j < 32; ++j) {
        float acc = 0.f;
#pragma unroll
        for (int i = 0; i < 16; ++i) acc = fmaf(xr[i], sW[i * 32 + j], acc);
        h[j] = acc;
    }

    float asr[4], adr[4];
#pragma unroll
    for (int hh = 0; hh < 4; ++hh) {
        float as = 0.f, ad = 0.f;
#pragma unroll
        for (int c = 0; c < 8; ++c) {
            as = fmaf(h[hh * 8 + c], sAs[hh * 8 + c], as);
            ad = fmaf(h[hh * 8 + c], sAd[hh * 8 + c], ad);
        }
        asr[hh] = as; adr[hh] = ad;
    }

    float4* h1p = (float4*)(h1 + (size_t)n * 32);
#pragma unroll
    for (int j = 0; j < 32; j += 4)
        h1p[j >> 2] = make_float4(h[j], h[j+1], h[j+2], h[j+3]);
    *(float4*)(a_src1 + (size_t)n * 4) = make_float4(asr[0], asr[1], asr[2], asr[3]);
    *(float4*)(a_dst1 + (size_t)n * 4) = make_float4(adr[0], adr[1], adr[2], adr[3]);
}

// ---------------------------------------------------------------------------
// CSR build: histogram -> 3-kernel exclusive scan -> scatter
// ---------------------------------------------------------------------------
__global__ __launch_bounds__(256) void khist(
    const int* __restrict__ dst, int* __restrict__ deg, int E)
{
    int e = blockIdx.x * 256 + threadIdx.x;
    if (e >= E) return;
    atomicAdd(deg + dst[e], 1);
}

// block b scans 1024 elements (256 threads x int4); writes per-element
// exclusive scan into rowptr, block total into bsum[b]
__global__ __launch_bounds__(256) void kscan_part(
    const int* __restrict__ deg, int* __restrict__ rowptr, int* __restrict__ bsum)
{
    __shared__ int sd[256];
    int b = blockIdx.x, tid = threadIdx.x;
    int4 v = ((const int4*)(deg + (size_t)b * 1024))[tid];
    int tsum = v.x + v.y + v.z + v.w;
    sd[tid] = tsum; __syncthreads();
    for (int off = 1; off < 256; off <<= 1) {
        int t = (tid >= off) ? sd[tid - off] : 0; __syncthreads();
        sd[tid] += t; __syncthreads();
    }
    int excl = sd[tid] - tsum;
    if (tid == 255) bsum[b] = sd[255];
    int4 o;
    o.x = excl; o.y = excl + v.x; o.z = excl + v.x + v.y; o.w = excl + v.x + v.y + v.z;
    ((int4*)(rowptr + (size_t)b * 1024))[tid] = o;
}

__global__ __launch_bounds__(256) void kscan_top(int* __restrict__ bsum, int nb)
{
    __shared__ int sd[256];
    int tid = threadIdx.x;
    int v = (tid < nb) ? bsum[tid] : 0;
    sd[tid] = v; __syncthreads();
    for (int off = 1; off < 256; off <<= 1) {
        int t = (tid >= off) ? sd[tid - off] : 0; __syncthreads();
        sd[tid] += t; __syncthreads();
    }
    if (tid < nb) bsum[tid] = sd[tid] - v;   // exclusive
}

__global__ __launch_bounds__(256) void kscan_add(
    int* __restrict__ rowptr, const int* __restrict__ bsum, int* __restrict__ cursor)
{
    int i = blockIdx.x * 256 + threadIdx.x;
    int v = rowptr[i] + bsum[i >> 10];
    rowptr[i] = v;
    cursor[i] = v;
}

__global__ __launch_bounds__(256) void kscatter(
    const int* __restrict__ src, const int* __restrict__ dst,
    int* __restrict__ cursor, int* __restrict__ esrc, int E)
{
    int e = blockIdx.x * 256 + threadIdx.x;
    if (e >= E) return;
    int s = src[e], d = dst[e];
    int p = atomicAdd(cursor + d, 1);
    esrc[p] = s;
}

// ---------------------------------------------------------------------------
// Gather layer 1 (fused: softmax-agg + bias + ELU + W2 projection -> h2)
// 8 lanes per destination node; lane l owns channels [4l, 4l+4), head = l>>1
// ---------------------------------------------------------------------------
__global__ __launch_bounds__(256) void kgather1(
    const int* __restrict__ rowptr, const int* __restrict__ esrc,
    const float* __restrict__ h1, const float* __restrict__ a_src1,
    const float* __restrict__ a_dst1,
    const float* __restrict__ b1, const float* __restrict__ W2,
    float* __restrict__ h2, int N)
{
    int tid = threadIdx.x;
    int g = tid >> 3, l = tid & 7;
    int d = blockIdx.x * 32 + g;
    if (d >= N) return;
    int hsel = l >> 1;
    int c0 = l * 4;

    int r0 = rowptr[d], r1 = rowptr[d + 1];
    float4 ad4 = *(const float4*)(a_dst1 + (size_t)d * 4);
    float adh = ((const float*)&ad4)[hsel];

    // self loop
    float4 asd = *(const float4*)(a_src1 + (size_t)d * 4);
    float wself = eexp(lrelu(((const float*)&asd)[hsel] + adh));
    float4 hv = *(const float4*)(h1 + (size_t)d * 32 + c0);
    float dsum = wself;
    float4 acc = make_float4(wself * hv.x, wself * hv.y, wself * hv.z, wself * hv.w);

    int p = r0;
    int s = (p < r1) ? esrc[p] : 0;
    while (p < r1) {
        int pn = p + 1;
        int sn = (pn < r1) ? esrc[pn] : 0;      // prefetch next src id
        float  ash = a_src1[(size_t)s * 4 + hsel];
        float4 hs  = *(const float4*)(h1 + (size_t)s * 32 + c0);
        float  w   = eexp(lrelu(ash + adh));
        dsum += w;
        acc.x = fmaf(w, hs.x, acc.x);
        acc.y = fmaf(w, hs.y, acc.y);
        acc.z = fmaf(w, hs.z, acc.z);
        acc.w = fmaf(w, hs.w, acc.w);
        s = sn; p = pn;
    }

    float inv = 1.f / (dsum + 1e-16f);
    float4 bb = *(const float4*)(b1 + c0);
    float4 ww = *(const float4*)(W2 + c0);
    float partial = 0.f, o;
    o = fmaf(acc.x, inv, bb.x); o = o > 0.f ? o : __expf(o) - 1.f; partial = fmaf(o, ww.x, partial);
    o = fmaf(acc.y, inv, bb.y); o = o > 0.f ? o : __expf(o) - 1.f; partial = fmaf(o, ww.y, partial);
    o = fmaf(acc.z, inv, bb.z); o = o > 0.f ? o : __expf(o) - 1.f; partial = fmaf(o, ww.z, partial);
    o = fmaf(acc.w, inv, bb.w); o = o > 0.f ? o : __expf(o) - 1.f; partial = fmaf(o, ww.w, partial);

    partial += __shfl_xor(partial, 1);
    partial += __shfl_xor(partial, 2);
    partial += __shfl_xor(partial, 4);
    if (l == 0) h2[d] = partial;
}

// ---------------------------------------------------------------------------
// Gather layer 2 (fused: softmax-agg + bias -> out), 1 thread per node
// ---------------------------------------------------------------------------
__global__ __launch_bounds__(256) void kgather2(
    const int* __restrict__ rowptr, const int* __restrict__ esrc,
    const float* __restrict__ h2,
    const float* __restrict__ att_src2, const float* __restrict__ att_dst2,
    const float* __restrict__ b2, float* __restrict__ out, int N)
{
    int n = blockIdx.x * 256 + threadIdx.x;
    if (n >= N) return;
    float s2 = att_src2[0], d2 = att_dst2[0];
    int r0 = rowptr[n], r1 = rowptr[n + 1];
    float h2d = h2[n];
    float add = h2d * d2;

    float wself = eexp(lrelu(fmaf(h2d, s2, add)));
    float den = wself, acc = wself * h2d;

    int p = r0;
    int s = (p < r1) ? esrc[p] : 0;
    while (p < r1) {
        int pn = p + 1;
        int sn = (pn < r1) ? esrc[pn] : 0;
        float hs = h2[s];
        float w = eexp(lrelu(fmaf(hs, s2, add)));
        den += w;
        acc = fmaf(w, hs, acc);
        s = sn; p = pn;
    }
    out[n] = acc / (den + 1e-16f) + b2[0];
}

extern "C" void kernel_launch(void* const* d_in, const int* in_sizes, int n_in,
                              void* d_out, int out_size, void* d_ws, size_t ws_size,
                              hipStream_t stream)
{
    const float* x        = (const float*)d_in[0];
    const int*   ei       = (const int*)d_in[1];
    const float* W1       = (const float*)d_in[2];
    const float* att_src1 = (const float*)d_in[3];
    const float* att_dst1 = (const float*)d_in[4];
    const float* b1       = (const float*)d_in[5];
    const float* W2       = (const float*)d_in[6];
    const float* att_src2 = (const float*)d_in[7];
    const float* att_dst2 = (const float*)d_in[8];
    const float* b2       = (const float*)d_in[9];

    const int N = in_sizes[0] / 16;
    const int E = in_sizes[1] / 2;
    const int* src = ei;
    const int* dst = ei + E;

    const int PAD = ((N + 1023) / 1024) * 1024;   // scan-padded node count
    const int NB  = PAD / 1024;                   // scan blocks (<=256)

    // workspace layout (4-byte elements)
    float* h1     = (float*)d_ws;                              // N*32
    float* a_src1 = h1     + (size_t)N * 32;                   // N*4
    float* a_dst1 = a_src1 + (size_t)N * 4;                    // N*4
    float* h2     = a_dst1 + (size_t)N * 4;                    // N
    int*   rowptr = (int*)(h2 + N);                            // PAD
    int*   degcur = rowptr + PAD;                              // PAD (deg, then cursor)
    int*   bsum   = degcur + PAD;                              // 256
    int*   esrc   = bsum + 256;                                // E

    const int nb_n = (N + 255) / 256;
    const int nb_e = (E + 255) / 256;

    hipMemsetAsync(degcur, 0, (size_t)PAD * sizeof(int), stream);

    k1_node<<<nb_n, 256, 0, stream>>>(x, W1, att_src1, att_dst1,
                                      h1, a_src1, a_dst1, N);
    khist<<<nb_e, 256, 0, stream>>>(dst, degcur, E);
    kscan_part<<<NB, 256, 0, stream>>>(degcur, rowptr, bsum);
    kscan_top<<<1, 256, 0, stream>>>(bsum, NB);
    kscan_add<<<PAD / 256, 256, 0, stream>>>(rowptr, bsum, degcur);
    kscatter<<<nb_e, 256, 0, stream>>>(src, dst, degcur, esrc, E);
    kgather1<<<(N + 31) / 32, 256, 0, stream>>>(rowptr, esrc, h1, a_src1, a_dst1,
                                                b1, W2, h2, N);
    kgather2<<<nb_n, 256, 0, stream>>>(rowptr, esrc, h2, att_src2, att_dst2,
                                       b2, (float*)d_out, N);
}